// Round 5
// baseline (266.898 us; speedup 1.0000x reference)
//
#include <hip/hip_runtime.h>

typedef __attribute__((ext_vector_type(4))) float f32x4;
typedef __attribute__((ext_vector_type(2))) float f32x2;
typedef __attribute__((ext_vector_type(8))) short bf16x8;

#define NEDGE 100000
#define NNODE 10000
#define INV40f 0.15811388300841897f
#define INV120f 0.09128709291752769f

__device__ inline short f2bf(float f) {
    unsigned u = __builtin_bit_cast(unsigned, f);
    u = (u + 0x7fffu + ((u >> 16) & 1u)) >> 16;
    return (short)u;
}

__device__ __forceinline__ float bperm(int byteIdx, float v) {
    return __builtin_bit_cast(float,
        __builtin_amdgcn_ds_bpermute(byteIdx, __builtin_bit_cast(int, v)));
}

#define MFMA16(A,B,C) __builtin_amdgcn_mfma_f32_16x16x32_bf16((A),(B),(C),0,0,0)

// prep: fc2_w -> fc2_wt [c][k] bf16 ; fc1_w -> fc1_wt [n][k] bf16 ; stats zero
__global__ __launch_bounds__(256) void prep(const float* __restrict__ fc1_w,
                                            const float* __restrict__ fc2_w,
                                            short* __restrict__ fc1_wt,
                                            short* __restrict__ fc2_wt,
                                            float* __restrict__ stats) {
    const int b = blockIdx.x, t = threadIdx.x;
    if (b < 400) {
        const int i = b*256 + t;              // 0..102399 = 64k x 1600c
        const int k = i / 1600, c = i - k*1600;
        fc2_wt[c*64 + k] = f2bf(fc2_w[i]);
    } else if (b < 416) {
        const int i = (b-400)*256 + t;        // 0..4095 = 64k x 64n
        fc1_wt[(i & 63)*64 + (i >> 6)] = f2bf(fc1_w[i]);
    } else {
        if (t < 72) stats[t] = 0.0f;
    }
}

// one block: LDS histogram of src + exclusive scan -> offsets[10001], cursor[10000]
__global__ __launch_bounds__(1024) void hist_scan(const int* __restrict__ edge_index,
                                                  int* __restrict__ offsets,
                                                  int* __restrict__ cursor) {
    __shared__ int lh[NNODE];
    __shared__ int part[1024];
    const int t = threadIdx.x;
    for (int n = t; n < NNODE; n += 1024) lh[n] = 0;
    __syncthreads();
    for (int e = t; e < NEDGE; e += 1024) atomicAdd(&lh[edge_index[e]], 1);
    __syncthreads();
    const int n0 = t * 10;                    // 1000 threads x 10 nodes exactly
    int s = 0;
    if (n0 < NNODE) {
        #pragma unroll
        for (int j = 0; j < 10; j++) s += lh[n0 + j];
    }
    part[t] = s;
    __syncthreads();
    for (int d = 1; d < 1024; d <<= 1) {
        const int v = (t >= d) ? part[t - d] : 0;
        __syncthreads();
        part[t] += v;
        __syncthreads();
    }
    if (n0 < NNODE) {
        int run = part[t] - s;
        #pragma unroll
        for (int j = 0; j < 10; j++) {
            offsets[n0 + j] = run; cursor[n0 + j] = run; run += lh[n0 + j];
        }
    }
    if (t == 0) offsets[NNODE] = NEDGE;
}

// 2 independent waves per block, 16 edges per wave, no __syncthreads.
// Swapped MFMA: D[m=weight-col j][n=edge e], lane(l15=e, lg): c[reg]=w-out[e][j=lg4+reg].
__global__ __launch_bounds__(128, 4) void edge_fused(
    const float* __restrict__ node_attr,
    const float* __restrict__ edge_attr,
    const float* __restrict__ edge_sh,
    const int*   __restrict__ edge_index,
    const float* __restrict__ fc1_b,
    const float* __restrict__ fc2_b,
    const short* __restrict__ fc1_wt,
    const short* __restrict__ fc2_wt,
    float* __restrict__ tp_out,
    int*   __restrict__ cursor)
{
    __shared__ __align__(16) char lds[4608];   // per wave: h_s 2048 + shb 256
    const int tid  = threadIdx.x;
    const int wid  = tid >> 6;
    const int wtid = tid & 63;
    const int l15  = wtid & 15;
    const int lg   = wtid >> 4;
    const int lg4  = lg * 4;
    const int e0   = blockIdx.x * 32 + wid * 16;
    char*  h_s = lds + wid * 2048;
    float* shb = (float*)(lds + 4096 + wid * 256);

    // ---- edge meta: lanes 0..15 of the wave own one edge each ----
    int dst_r = 0, slot_r = 0;
    if (wtid < 16) {
        dst_r = edge_index[NEDGE + e0 + wtid];
        const int src = edge_index[e0 + wtid];
        const f32x4 sh_r = *(const f32x4*)(edge_sh + (size_t)(e0 + wtid) * 4);
        slot_r = atomicAdd(&cursor[src], 1);   // CSR slot for this edge
        *(f32x4*)(shb + wtid * 4) = sh_r;
    }

    // ---- fc1 A loads (streaming) ----
    const float* pa = edge_attr + (size_t)(e0 + l15) * 64 + lg * 8;
    const f32x4 va0 = *(const f32x4*)(pa);
    const f32x4 va1 = *(const f32x4*)(pa + 4);
    const f32x4 va2 = *(const f32x4*)(pa + 32);
    const f32x4 va3 = *(const f32x4*)(pa + 36);

    // ---- per-lane table slice gather: edge e=l15, u-slice by lg ----
    const int dstm = __shfl(dst_r, l15, 64);
    const int p_e  = __shfl(slot_r, l15, 64);
    const float* nap = node_attr + (size_t)dstm * 56;
    const f32x4 x0a = *(const f32x4*)(nap + lg*8);
    const f32x4 x0b = *(const f32x4*)(nap + lg*8 + 4);
    const f32x2 x1a = *(const f32x2*)(nap + 32 + lg*6);
    const f32x2 x1b = *(const f32x2*)(nap + 34 + lg*6);
    const f32x2 x1c = *(const f32x2*)(nap + 36 + lg*6);
    const f32x4 shv = *(const f32x4*)(shb + l15 * 4);   // same-wave LDS RAW, in-order

    // ---- register tables (24 VGPRs) ----
    float c00r[8], cb1r[8], c10r[6], c11r[2];
    {
        const float s0 = shv[0];
        #pragma unroll
        for (int j = 0; j < 4; j++) {
            cb1r[j]   = INV40f * x0a[j];
            cb1r[4+j] = INV40f * x0b[j];
            c00r[j]   = s0 * cb1r[j];
            c00r[4+j] = s0 * cb1r[4+j];
        }
        const float i40s0 = INV40f * s0;
        c10r[0] = i40s0 * x1a[0]; c10r[1] = i40s0 * x1a[1]; c10r[2] = i40s0 * x1b[0];
        c10r[3] = i40s0 * x1b[1]; c10r[4] = i40s0 * x1c[0]; c10r[5] = i40s0 * x1c[1];
        c11r[0] = INV120f * (x1a[0]*shv[1] + x1a[1]*shv[2] + x1b[0]*shv[3]);
        c11r[1] = INV120f * (x1b[1]*shv[1] + x1c[0]*shv[2] + x1c[1]*shv[3]);
    }
    // bpermute lane indices: value for (e=l15, u) lives at lane (u>>3)*16 + l15 (c00/cb1)
    int vidx[4];
    #pragma unroll
    for (int g = 0; g < 4; g++) vidx[g] = (g*16 + l15) * 4;

    // ---- fc1: h = relu(ea @ fc1_w + b), staged to swizzled LDS for transpose ----
    bf16x8 a0, a1;
    #pragma unroll
    for (int i = 0; i < 4; i++) {
        a0[i] = f2bf(va0[i]); a0[4+i] = f2bf(va1[i]);
        a1[i] = f2bf(va2[i]); a1[4+i] = f2bf(va3[i]);
    }
    #pragma unroll
    for (int nf0 = 0; nf0 < 4; nf0++) {
        const bf16x8 b0 = *(const bf16x8*)(fc1_wt + (nf0*16 + l15)*64 + lg*8);
        const bf16x8 b1 = *(const bf16x8*)(fc1_wt + (nf0*16 + l15)*64 + 32 + lg*8);
        const float bias = fc1_b[nf0*16 + l15];
        f32x4 c = {bias, bias, bias, bias};
        c = MFMA16(a0, b0, c);
        c = MFMA16(a1, b1, c);
        #pragma unroll
        for (int reg = 0; reg < 4; reg++) {
            const int row = lg4 + reg;
            *(short*)(h_s + ((row*128 + (nf0*16 + l15)*2) ^ ((row & 7) << 4))) =
                f2bf(fmaxf(c[reg], 0.0f));
        }
    }
    // read back transposed: lane(l15=e) holds h[e][k = lg*8..+7]
    const bf16x8 ha0 = *(const bf16x8*)(h_s + ((l15*128 +      lg*16) ^ ((l15 & 7) << 4)));
    const bf16x8 ha1 = *(const bf16x8*)(h_s + ((l15*128 + 64 + lg*16) ^ ((l15 & 7) << 4)));

    // ---- fc2 (swapped operands) + in-register TP consume ----
    const short* pB = fc2_wt + l15*64 + lg*8;    // A-frag: w[col=nf*16+l15][k]
    const int usel = lg >> 1;
    float acc0[2][4] = {{0,0,0,0},{0,0,0,0}};
    float ab1[4] = {0,0,0,0};
    float b2v[12] = {};

    // region w00: nf 0..63 ; u = nf>>1 (uniform), out0 w = (nf&1)*16 + j
    #pragma unroll
    for (int nf = 0; nf < 64; nf++) {
        const bf16x8 b0 = *(const bf16x8*)(pB + nf*1024);
        const bf16x8 b1 = *(const bf16x8*)(pB + nf*1024 + 32);
        f32x4 c = *(const f32x4*)(fc2_b + nf*16 + lg4);
        c = MFMA16(b0, ha0, c);
        c = MFMA16(b1, ha1, c);
        const int u = nf >> 1, hi = nf & 1;
        const float cv = bperm(vidx[u >> 3], c00r[u & 7]);
        #pragma unroll
        for (int reg = 0; reg < 4; reg++) acc0[hi][reg] += cv * c[reg];
    }
    // region w01: nf 64..79 ; u = 2*nfl + usel, w = (lg&1)*4 + reg
    #pragma unroll
    for (int nfl = 0; nfl < 16; nfl++) {
        const int nf = 64 + nfl;
        const bf16x8 b0 = *(const bf16x8*)(pB + nf*1024);
        const bf16x8 b1 = *(const bf16x8*)(pB + nf*1024 + 32);
        f32x4 c = *(const f32x4*)(fc2_b + nf*16 + lg4);
        c = MFMA16(b0, ha0, c);
        c = MFMA16(b1, ha1, c);
        const int r0 = (2*nfl) & 7, g = nfl >> 2;
        const float e0v = bperm(vidx[g], cb1r[r0]);
        const float e1v = bperm(vidx[g], cb1r[r0 + 1]);
        const float cv = usel ? e1v : e0v;
        #pragma unroll
        for (int reg = 0; reg < 4; reg++) ab1[reg] += cv * c[reg];
    }
    // region w10: nf 80..83 ; u = 2*nfl + usel, w = (lg&1)*4 + reg
    #pragma unroll
    for (int nfl = 0; nfl < 4; nfl++) {
        const int nf = 80 + nfl;
        const bf16x8 b0 = *(const bf16x8*)(pB + nf*1024);
        const bf16x8 b1 = *(const bf16x8*)(pB + nf*1024 + 32);
        f32x4 c = *(const f32x4*)(fc2_b + nf*16 + lg4);
        c = MFMA16(b0, ha0, c);
        c = MFMA16(b1, ha1, c);
        #pragma unroll
        for (int i = 0; i < 3; i++) {
            const float e0v = bperm(vidx[nfl], c10r[i]);
            const float e1v = bperm(vidx[nfl], c10r[3 + i]);
            const float cv = usel ? e1v : e0v;
            #pragma unroll
            for (int reg = 0; reg < 4; reg++) b2v[reg*3 + i] += cv * c[reg];
        }
    }
    // region w11: nf 84..99 ; u' = nfl>>1 (uniform), out0 w = (nfl&1)*16 + j
    #pragma unroll
    for (int nfl = 0; nfl < 16; nfl++) {
        const int nf = 84 + nfl;
        const bf16x8 b0 = *(const bf16x8*)(pB + nf*1024);
        const bf16x8 b1 = *(const bf16x8*)(pB + nf*1024 + 32);
        f32x4 c = *(const f32x4*)(fc2_b + nf*16 + lg4);
        c = MFMA16(b0, ha0, c);
        c = MFMA16(b1, ha1, c);
        const int up = nfl >> 1, hi = nfl & 1;
        const float cv = bperm(vidx[up >> 1], c11r[up & 1]);
        #pragma unroll
        for (int reg = 0; reg < 4; reg++) acc0[hi][reg] += cv * c[reg];
    }

    // ---- emit directly to permuted CSR row p_e ----
    float* orow = tp_out + (size_t)p_e * 56;
    {
        const f32x4 o0 = {acc0[0][0], acc0[0][1], acc0[0][2], acc0[0][3]};
        const f32x4 o1 = {acc0[1][0], acc0[1][1], acc0[1][2], acc0[1][3]};
        *(f32x4*)(orow + lg4)      = o0;
        *(f32x4*)(orow + 16 + lg4) = o1;
    }
    #pragma unroll
    for (int reg = 0; reg < 4; reg++) ab1[reg] += __shfl_xor(ab1[reg], 32, 64);
    #pragma unroll
    for (int m = 0; m < 12; m++) b2v[m] += __shfl_xor(b2v[m], 32, 64);
    if (lg < 2) {
        float ov[12];
        #pragma unroll
        for (int reg = 0; reg < 4; reg++) {
            ov[reg*3 + 0] = shv[1] * ab1[reg] + b2v[reg*3 + 0];
            ov[reg*3 + 1] = shv[2] * ab1[reg] + b2v[reg*3 + 1];
            ov[reg*3 + 2] = shv[3] * ab1[reg] + b2v[reg*3 + 2];
        }
        float* p1 = orow + 32 + lg * 12;
        *(f32x4*)(p1)     = f32x4{ov[0], ov[1], ov[2],  ov[3]};
        *(f32x4*)(p1 + 4) = f32x4{ov[4], ov[5], ov[6],  ov[7]};
        *(f32x4*)(p1 + 8) = f32x4{ov[8], ov[9], ov[10], ov[11]};
    }
}

// contiguous-segment mean + residual + BN partial stats
__global__ __launch_bounds__(256) void node_agg(
    const float* __restrict__ tp_out, const int* __restrict__ offsets,
    const float* __restrict__ node_attr, float* __restrict__ out,
    float* __restrict__ stats)
{
    __shared__ float part[72];
    const int tid = threadIdx.x;
    if (tid < 72) part[tid] = 0.0f;
    __syncthreads();
    const int n = blockIdx.x * 16 + (tid >> 4);
    const int q = tid & 15;
    if (n < NNODE && q < 14) {
        const int st = offsets[n], en = offsets[n + 1];
        f32x4 acc = {0.f, 0.f, 0.f, 0.f};
        #pragma unroll 2
        for (int r = st; r < en; r++)
            acc += *(const f32x4*)(tp_out + (size_t)r * 56 + q*4);
        const float inv = 1.0f / fmaxf((float)(en - st), 1.0f);
        const int c0 = q * 4;
        const f32x4 res = *(const f32x4*)(node_attr + (size_t)n*56 + c0);
        f32x4 val;
        #pragma unroll
        for (int j = 0; j < 4; j++) {
            val[j] = acc[j] * inv + res[j];
            const int c = c0 + j;
            if (c < 32) {
                atomicAdd(&part[c], val[j]);
                atomicAdd(&part[32 + c], val[j] * val[j]);
            } else {
                atomicAdd(&part[64 + (c - 32) / 3], val[j] * val[j]);
            }
        }
        *(f32x4*)(out + (size_t)n*56 + c0) = val;
    }
    __syncthreads();
    if (tid < 72) unsafeAtomicAdd(&stats[tid], part[tid]);
}

__global__ __launch_bounds__(256) void node_norm(
    float* __restrict__ out, const float* __restrict__ stats,
    const float* __restrict__ g0, const float* __restrict__ b0,
    const float* __restrict__ g1)
{
    const int id = blockIdx.x * 256 + threadIdx.x;
    if (id >= NNODE * 56) return;
    const int c = id % 56;
    float val = out[id];
    if (c < 32) {
        const float m   = stats[c]      * (1.0f / NNODE);
        const float ex2 = stats[32 + c] * (1.0f / NNODE);
        const float var = ex2 - m * m;
        val = (val - m) * rsqrtf(var + 1e-5f) * g0[c] + b0[c];
    } else {
        const int v = (c - 32) / 3;
        const float vn = stats[64 + v] * (1.0f / (3.0f * NNODE));
        val = val * rsqrtf(vn + 1e-5f) * g1[v];
    }
    out[id] = val;
}

extern "C" void kernel_launch(void* const* d_in, const int* in_sizes, int n_in,
                              void* d_out, int out_size, void* d_ws, size_t ws_size,
                              hipStream_t stream) {
    const float* node_attr = (const float*)d_in[0];
    const float* edge_attr = (const float*)d_in[1];
    const float* edge_sh   = (const float*)d_in[2];
    const int*   edge_index= (const int*)  d_in[3];
    const float* fc1_w     = (const float*)d_in[4];
    const float* fc1_b     = (const float*)d_in[5];
    const float* fc2_w     = (const float*)d_in[6];
    const float* fc2_b     = (const float*)d_in[7];
    const float* g0        = (const float*)d_in[8];
    const float* b0        = (const float*)d_in[9];
    const float* g1        = (const float*)d_in[10];
    float* out = (float*)d_out;

    char* ws = (char*)d_ws;
    // stats(288) | offsets 10001 int (40004 -> pad 40032) | cursor 40000 |
    // fc1_wt 8192 | fc2_wt 204800 | tp_out 22.4MB
    float* stats   = (float*)(ws + 0);
    int*   offsets = (int*)  (ws + 288);
    int*   cursor  = (int*)  (ws + 40320);
    short* fc1_wt  = (short*)(ws + 80320);
    short* fc2_wt  = (short*)(ws + 88512);
    float* tp_out  = (float*)(ws + 293312);

    prep<<<417, 256, 0, stream>>>(fc1_w, fc2_w, fc1_wt, fc2_wt, stats);
    hist_scan<<<1, 1024, 0, stream>>>(edge_index, offsets, cursor);
    edge_fused<<<3125, 128, 0, stream>>>(node_attr, edge_attr, edge_sh, edge_index,
                                         fc1_b, fc2_b, fc1_wt, fc2_wt, tp_out, cursor);
    node_agg<<<625, 256, 0, stream>>>(tp_out, offsets, node_attr, out, stats);
    node_norm<<<2188, 256, 0, stream>>>(out, stats, g0, b0, g1);
}

// Round 6
// 248.462 us; speedup vs baseline: 1.0742x; 1.0742x over previous
//
#include <hip/hip_runtime.h>

typedef __attribute__((ext_vector_type(4))) float f32x4;
typedef __attribute__((ext_vector_type(2))) float f32x2;
typedef __attribute__((ext_vector_type(8))) short bf16x8;

#define NEDGE 100000
#define NNODE 10000
#define INV40f 0.15811388300841897f
#define INV120f 0.09128709291752769f
#define PF 6

__device__ inline short f2bf(float f) {
    unsigned u = __builtin_bit_cast(unsigned, f);
    u = (u + 0x7fffu + ((u >> 16) & 1u)) >> 16;
    return (short)u;
}

__device__ __forceinline__ float bperm(int byteIdx, float v) {
    return __builtin_bit_cast(float,
        __builtin_amdgcn_ds_bpermute(byteIdx, __builtin_bit_cast(int, v)));
}

#define MFMA16(A,B,C) __builtin_amdgcn_mfma_f32_16x16x32_bf16((A),(B),(C),0,0,0)

// prep: fc2_w -> fc2_wt [c][k] bf16 ; fc1_w -> fc1_wt [n][k] bf16 ; zero stats+hist
__global__ __launch_bounds__(256) void prep(const float* __restrict__ fc1_w,
                                            const float* __restrict__ fc2_w,
                                            short* __restrict__ fc1_wt,
                                            short* __restrict__ fc2_wt,
                                            float* __restrict__ stats,
                                            int* __restrict__ hist) {
    const int b = blockIdx.x, t = threadIdx.x;
    if (b < 400) {
        const int i = b*256 + t;              // 64k x 1600c
        const int k = i / 1600, c = i - k*1600;
        fc2_wt[c*64 + k] = f2bf(fc2_w[i]);
    } else if (b < 416) {
        const int i = (b-400)*256 + t;        // 64k x 64n
        fc1_wt[(i & 63)*64 + (i >> 6)] = f2bf(fc1_w[i]);
    } else if (b == 416) {
        if (t < 72) stats[t] = 0.0f;
    } else {
        const int i = (b-417)*256 + t;
        if (i < NNODE) hist[i] = 0;
    }
}

// One wave (64 threads) owns 16 edges; no __syncthreads; deep register prefetch.
__global__ __launch_bounds__(64, 2) void edge_fused(
    const float* __restrict__ node_attr,
    const float* __restrict__ edge_attr,
    const float* __restrict__ edge_sh,
    const int*   __restrict__ edge_index,
    const float* __restrict__ fc1_b,
    const float* __restrict__ fc2_b,
    const short* __restrict__ fc1_wt,
    const short* __restrict__ fc2_wt,
    float* __restrict__ tp_out,
    int*   __restrict__ hist)
{
    __shared__ __align__(16) char lds[2304];   // h_s 2048 + shb 256
    char*  h_s = lds;
    float* shb = (float*)(lds + 2048);

    const int tid = threadIdx.x;
    const int l15 = tid & 15;
    const int lg  = tid >> 4;
    const int lg4 = lg * 4;
    const int e0  = blockIdx.x * 16;

    // ---- edge meta ----
    int dst_r = 0;
    if (tid < 16) {
        dst_r = edge_index[NEDGE + e0 + tid];
        const int src = edge_index[e0 + tid];
        const f32x4 sh_r = *(const f32x4*)(edge_sh + (size_t)(e0 + tid) * 4);
        atomicAdd(&hist[src], 1);
        *(f32x4*)(shb + tid * 4) = sh_r;
    }

    // ---- fc1 A loads (streaming) ----
    const float* pa = edge_attr + (size_t)(e0 + l15) * 64 + lg * 8;
    const f32x4 va0 = *(const f32x4*)(pa);
    const f32x4 va1 = *(const f32x4*)(pa + 4);
    const f32x4 va2 = *(const f32x4*)(pa + 32);
    const f32x4 va3 = *(const f32x4*)(pa + 36);

    // ---- per-lane table slice gather: edge e=l15, u-slice by lg ----
    const int dstm = __shfl(dst_r, l15, 64);
    const float* nap = node_attr + (size_t)dstm * 56;
    const f32x4 x0a = *(const f32x4*)(nap + lg*8);
    const f32x4 x0b = *(const f32x4*)(nap + lg*8 + 4);
    const f32x2 x1a = *(const f32x2*)(nap + 32 + lg*6);
    const f32x2 x1b = *(const f32x2*)(nap + 34 + lg*6);
    const f32x2 x1c = *(const f32x2*)(nap + 36 + lg*6);
    const f32x4 shv = *(const f32x4*)(shb + l15 * 4);   // same-wave LDS RAW, in-order

    // ---- register tables (24 VGPRs) ----
    float c00r[8], cb1r[8], c10r[6], c11r[2];
    {
        const float s0 = shv[0];
        #pragma unroll
        for (int j = 0; j < 4; j++) {
            cb1r[j]   = INV40f * x0a[j];
            cb1r[4+j] = INV40f * x0b[j];
            c00r[j]   = s0 * cb1r[j];
            c00r[4+j] = s0 * cb1r[4+j];
        }
        const float i40s0 = INV40f * s0;
        c10r[0] = i40s0 * x1a[0]; c10r[1] = i40s0 * x1a[1]; c10r[2] = i40s0 * x1b[0];
        c10r[3] = i40s0 * x1b[1]; c10r[4] = i40s0 * x1c[0]; c10r[5] = i40s0 * x1c[1];
        c11r[0] = INV120f * (x1a[0]*shv[1] + x1a[1]*shv[2] + x1b[0]*shv[3]);
        c11r[1] = INV120f * (x1b[1]*shv[1] + x1c[0]*shv[2] + x1c[1]*shv[3]);
    }
    int vidx[4];
    #pragma unroll
    for (int g = 0; g < 4; g++) vidx[g] = (g*16 + l15) * 4;

    // ---- fc1: h = relu(ea @ fc1_w + b) -> swizzled LDS (transpose) ----
    bf16x8 a0, a1;
    #pragma unroll
    for (int i = 0; i < 4; i++) {
        a0[i] = f2bf(va0[i]); a0[4+i] = f2bf(va1[i]);
        a1[i] = f2bf(va2[i]); a1[4+i] = f2bf(va3[i]);
    }
    #pragma unroll
    for (int nf0 = 0; nf0 < 4; nf0++) {
        const bf16x8 b0 = *(const bf16x8*)(fc1_wt + (nf0*16 + l15)*64 + lg*8);
        const bf16x8 b1 = *(const bf16x8*)(fc1_wt + (nf0*16 + l15)*64 + 32 + lg*8);
        const float bias = fc1_b[nf0*16 + l15];
        f32x4 c = {bias, bias, bias, bias};
        c = MFMA16(a0, b0, c);
        c = MFMA16(a1, b1, c);
        #pragma unroll
        for (int reg = 0; reg < 4; reg++) {
            const int row = lg4 + reg;
            *(short*)(h_s + ((row*128 + (nf0*16 + l15)*2) ^ ((row & 7) << 4))) =
                f2bf(fmaxf(c[reg], 0.0f));
        }
    }
    const bf16x8 ha0 = *(const bf16x8*)(h_s + ((l15*128 +      lg*16) ^ ((l15 & 7) << 4)));
    const bf16x8 ha1 = *(const bf16x8*)(h_s + ((l15*128 + 64 + lg*16) ^ ((l15 & 7) << 4)));

    // ---- fc2 (swapped operands) + in-register TP consume, PF-deep prefetch ----
    const short* pB = fc2_wt + l15*64 + lg*8;
    const int usel = lg >> 1;
    float acc0[2][4] = {{0,0,0,0},{0,0,0,0}};
    float ab1[4] = {0,0,0,0};
    float b2v[12] = {};

    bf16x8 qb0[PF], qb1[PF];
    f32x4  qc[PF];
    #pragma unroll
    for (int i = 0; i < PF; i++) {
        qb0[i] = *(const bf16x8*)(pB + i*1024);
        qb1[i] = *(const bf16x8*)(pB + i*1024 + 32);
        qc[i]  = *(const f32x4*)(fc2_b + i*16 + lg4);
    }
#define PREFETCH(NF) do { const int _n = (NF); if (_n < 100) { \
        const int _s = _n % PF; \
        qb0[_s] = *(const bf16x8*)(pB + _n*1024); \
        qb1[_s] = *(const bf16x8*)(pB + _n*1024 + 32); \
        qc[_s]  = *(const f32x4*)(fc2_b + _n*16 + lg4); } } while (0)

    // region w00: nf 0..63 ; u = nf>>1 (uniform)
    #pragma unroll
    for (int nf = 0; nf < 64; nf++) {
        const int s = nf % PF;
        const bf16x8 b0 = qb0[s], b1 = qb1[s];
        f32x4 c = qc[s];
        PREFETCH(nf + PF);
        c = MFMA16(b0, ha0, c);
        c = MFMA16(b1, ha1, c);
        const int u = nf >> 1, hi = nf & 1;
        const float cv = bperm(vidx[u >> 3], c00r[u & 7]);
        #pragma unroll
        for (int reg = 0; reg < 4; reg++) acc0[hi][reg] += cv * c[reg];
    }
    // region w01: nf 64..79
    #pragma unroll
    for (int nfl = 0; nfl < 16; nfl++) {
        const int nf = 64 + nfl;
        const int s = nf % PF;
        const bf16x8 b0 = qb0[s], b1 = qb1[s];
        f32x4 c = qc[s];
        PREFETCH(nf + PF);
        c = MFMA16(b0, ha0, c);
        c = MFMA16(b1, ha1, c);
        const int r0 = (2*nfl) & 7, g = nfl >> 2;
        const float e0v = bperm(vidx[g], cb1r[r0]);
        const float e1v = bperm(vidx[g], cb1r[r0 + 1]);
        const float cv = usel ? e1v : e0v;
        #pragma unroll
        for (int reg = 0; reg < 4; reg++) ab1[reg] += cv * c[reg];
    }
    // region w10: nf 80..83
    #pragma unroll
    for (int nfl = 0; nfl < 4; nfl++) {
        const int nf = 80 + nfl;
        const int s = nf % PF;
        const bf16x8 b0 = qb0[s], b1 = qb1[s];
        f32x4 c = qc[s];
        PREFETCH(nf + PF);
        c = MFMA16(b0, ha0, c);
        c = MFMA16(b1, ha1, c);
        #pragma unroll
        for (int i = 0; i < 3; i++) {
            const float e0v = bperm(vidx[nfl], c10r[i]);
            const float e1v = bperm(vidx[nfl], c10r[3 + i]);
            const float cv = usel ? e1v : e0v;
            #pragma unroll
            for (int reg = 0; reg < 4; reg++) b2v[reg*3 + i] += cv * c[reg];
        }
    }
    // region w11: nf 84..99
    #pragma unroll
    for (int nfl = 0; nfl < 16; nfl++) {
        const int nf = 84 + nfl;
        const int s = nf % PF;
        const bf16x8 b0 = qb0[s], b1 = qb1[s];
        f32x4 c = qc[s];
        PREFETCH(nf + PF);
        c = MFMA16(b0, ha0, c);
        c = MFMA16(b1, ha1, c);
        const int up = nfl >> 1, hi = nfl & 1;
        const float cv = bperm(vidx[up >> 1], c11r[up & 1]);
        #pragma unroll
        for (int reg = 0; reg < 4; reg++) acc0[hi][reg] += cv * c[reg];
    }
#undef PREFETCH

    // ---- emit edge-ordered coalesced rows ----
    float* orow = tp_out + (size_t)(e0 + l15) * 56;
    {
        const f32x4 o0 = {acc0[0][0], acc0[0][1], acc0[0][2], acc0[0][3]};
        const f32x4 o1 = {acc0[1][0], acc0[1][1], acc0[1][2], acc0[1][3]};
        *(f32x4*)(orow + lg4)      = o0;
        *(f32x4*)(orow + 16 + lg4) = o1;
    }
    #pragma unroll
    for (int reg = 0; reg < 4; reg++) ab1[reg] += __shfl_xor(ab1[reg], 32, 64);
    #pragma unroll
    for (int m = 0; m < 12; m++) b2v[m] += __shfl_xor(b2v[m], 32, 64);
    if (lg < 2) {
        float ov[12];
        #pragma unroll
        for (int reg = 0; reg < 4; reg++) {
            ov[reg*3 + 0] = shv[1] * ab1[reg] + b2v[reg*3 + 0];
            ov[reg*3 + 1] = shv[2] * ab1[reg] + b2v[reg*3 + 1];
            ov[reg*3 + 2] = shv[3] * ab1[reg] + b2v[reg*3 + 2];
        }
        float* p1 = orow + 32 + lg * 12;
        *(f32x4*)(p1)     = f32x4{ov[0], ov[1], ov[2],  ov[3]};
        *(f32x4*)(p1 + 4) = f32x4{ov[4], ov[5], ov[6],  ov[7]};
        *(f32x4*)(p1 + 8) = f32x4{ov[8], ov[9], ov[10], ov[11]};
    }
}

// exclusive prefix scan of hist[10000] -> offsets[10001], cursor
__global__ __launch_bounds__(256) void scan_hist(const int* __restrict__ hist,
                                                 int* __restrict__ offsets,
                                                 int* __restrict__ cursor) {
    __shared__ int part[256];
    const int t = threadIdx.x;
    const int n0 = t * 40;
    int s = 0;
    for (int j = 0; j < 40; j++) { const int n = n0 + j; s += (n < NNODE) ? hist[n] : 0; }
    part[t] = s;
    __syncthreads();
    for (int d = 1; d < 256; d <<= 1) {
        const int v = (t >= d) ? part[t - d] : 0;
        __syncthreads();
        part[t] += v;
        __syncthreads();
    }
    int run = part[t] - s;
    for (int j = 0; j < 40; j++) {
        const int n = n0 + j;
        if (n < NNODE) { offsets[n] = run; cursor[n] = run; run += hist[n]; }
    }
    if (t == 0) offsets[NNODE] = NEDGE;
}

__global__ __launch_bounds__(256) void fill_perm(const int* __restrict__ edge_index,
                                                 int* __restrict__ cursor,
                                                 int* __restrict__ perm) {
    const int e = blockIdx.x * 256 + threadIdx.x;
    if (e < NEDGE) {
        const int s = edge_index[e];
        const int p = atomicAdd(&cursor[s], 1);
        perm[p] = e;
    }
}

// gather-based segment mean + residual + BN partial stats (16 threads/node, f32x4)
__global__ __launch_bounds__(256) void node_agg(
    const float* __restrict__ tp_out, const int* __restrict__ offsets,
    const int* __restrict__ perm,
    const float* __restrict__ node_attr, float* __restrict__ out,
    float* __restrict__ stats)
{
    __shared__ float part[72];
    const int tid = threadIdx.x;
    if (tid < 72) part[tid] = 0.0f;
    __syncthreads();
    const int n = blockIdx.x * 16 + (tid >> 4);
    const int q = tid & 15;
    if (n < NNODE && q < 14) {
        const int st = offsets[n], en = offsets[n + 1];
        f32x4 acc = {0.f, 0.f, 0.f, 0.f};
        for (int r = st; r < en; r++)
            acc += *(const f32x4*)(tp_out + (size_t)perm[r] * 56 + q*4);
        const float inv = 1.0f / fmaxf((float)(en - st), 1.0f);
        const int c0 = q * 4;
        const f32x4 res = *(const f32x4*)(node_attr + (size_t)n*56 + c0);
        f32x4 val;
        #pragma unroll
        for (int j = 0; j < 4; j++) {
            val[j] = acc[j] * inv + res[j];
            const int c = c0 + j;
            if (c < 32) {
                atomicAdd(&part[c], val[j]);
                atomicAdd(&part[32 + c], val[j] * val[j]);
            } else {
                atomicAdd(&part[64 + (c - 32) / 3], val[j] * val[j]);
            }
        }
        *(f32x4*)(out + (size_t)n*56 + c0) = val;
    }
    __syncthreads();
    if (tid < 72) unsafeAtomicAdd(&stats[tid], part[tid]);
}

__global__ __launch_bounds__(256) void node_norm(
    float* __restrict__ out, const float* __restrict__ stats,
    const float* __restrict__ g0, const float* __restrict__ b0,
    const float* __restrict__ g1)
{
    const int id = blockIdx.x * 256 + threadIdx.x;
    if (id >= NNODE * 56) return;
    const int c = id % 56;
    float val = out[id];
    if (c < 32) {
        const float m   = stats[c]      * (1.0f / NNODE);
        const float ex2 = stats[32 + c] * (1.0f / NNODE);
        const float var = ex2 - m * m;
        val = (val - m) * rsqrtf(var + 1e-5f) * g0[c] + b0[c];
    } else {
        const int v = (c - 32) / 3;
        const float vn = stats[64 + v] * (1.0f / (3.0f * NNODE));
        val = val * rsqrtf(vn + 1e-5f) * g1[v];
    }
    out[id] = val;
}

extern "C" void kernel_launch(void* const* d_in, const int* in_sizes, int n_in,
                              void* d_out, int out_size, void* d_ws, size_t ws_size,
                              hipStream_t stream) {
    const float* node_attr = (const float*)d_in[0];
    const float* edge_attr = (const float*)d_in[1];
    const float* edge_sh   = (const float*)d_in[2];
    const int*   edge_index= (const int*)  d_in[3];
    const float* fc1_w     = (const float*)d_in[4];
    const float* fc1_b     = (const float*)d_in[5];
    const float* fc2_w     = (const float*)d_in[6];
    const float* fc2_b     = (const float*)d_in[7];
    const float* g0        = (const float*)d_in[8];
    const float* b0        = (const float*)d_in[9];
    const float* g1        = (const float*)d_in[10];
    float* out = (float*)d_out;

    char* ws = (char*)d_ws;
    // stats 288 | hist @288 (40000) | offsets @40288 (40004) | cursor @80320 (40000) |
    // perm @120320 (400000) | fc1_wt @520320 (8192) | fc2_wt @528512 (204800) | tp_out @733312 (22.4MB)
    float* stats   = (float*)(ws + 0);
    int*   hist    = (int*)  (ws + 288);
    int*   offsets = (int*)  (ws + 40288);
    int*   cursor  = (int*)  (ws + 80320);
    int*   perm    = (int*)  (ws + 120320);
    short* fc1_wt  = (short*)(ws + 520320);
    short* fc2_wt  = (short*)(ws + 528512);
    float* tp_out  = (float*)(ws + 733312);

    prep<<<457, 256, 0, stream>>>(fc1_w, fc2_w, fc1_wt, fc2_wt, stats, hist);
    edge_fused<<<6250, 64, 0, stream>>>(node_attr, edge_attr, edge_sh, edge_index,
                                        fc1_b, fc2_b, fc1_wt, fc2_wt, tp_out, hist);
    scan_hist<<<1, 256, 0, stream>>>(hist, offsets, cursor);
    fill_perm<<<391, 256, 0, stream>>>(edge_index, cursor, perm);
    node_agg<<<625, 256, 0, stream>>>(tp_out, offsets, perm, node_attr, out, stats);
    node_norm<<<2188, 256, 0, stream>>>(out, stats, g0, b0, g1);
}

// Round 7
// 110.765 us; speedup vs baseline: 2.4096x; 2.2431x over previous
//
#include <hip/hip_runtime.h>

typedef __attribute__((ext_vector_type(4))) float f32x4;
typedef __attribute__((ext_vector_type(2))) float f32x2;
typedef __attribute__((ext_vector_type(8))) short bf16x8;

#define NEDGE 100000
#define NNODE 10000
#define INV40f 0.15811388300841897f
#define INV120f 0.09128709291752769f

__device__ inline short f2bf(float f) {
    unsigned u = __builtin_bit_cast(unsigned, f);
    u = (u + 0x7fffu + ((u >> 16) & 1u)) >> 16;
    return (short)u;
}

__device__ __forceinline__ float bperm(int byteIdx, float v) {
    return __builtin_bit_cast(float,
        __builtin_amdgcn_ds_bpermute(byteIdx, __builtin_bit_cast(int, v)));
}

// async global->LDS, 16B per lane; LDS dest = wave-uniform base + lane*16
__device__ __forceinline__ void stage16(const void* gsrc, void* ldst) {
    __builtin_amdgcn_global_load_lds(
        (const __attribute__((address_space(1))) unsigned*)gsrc,
        (__attribute__((address_space(3))) unsigned*)(unsigned long long)(uintptr_t)ldst,
        16, 0, 0);
}

#define MFMA16(A,B,C) __builtin_amdgcn_mfma_f32_16x16x32_bf16((A),(B),(C),0,0,0)

// prep: fc2_w [64k][1600c] -> fc2_wt [c][k] bf16 via LDS transpose (coalesced both ways);
// fc1_w -> fc1_wt [n][k]; zero stats + hist.
__global__ __launch_bounds__(256) void prep(const float* __restrict__ fc1_w,
                                            const float* __restrict__ fc2_w,
                                            short* __restrict__ fc1_wt,
                                            short* __restrict__ fc2_wt,
                                            float* __restrict__ stats,
                                            int* __restrict__ hist) {
    const int b = blockIdx.x, t = threadIdx.x;
    if (b < 25) {
        __shared__ short tile[64 * 66];
        const int c0 = b * 64;
        #pragma unroll
        for (int rep = 0; rep < 16; rep++) {
            const int idx = rep * 256 + t;         // 0..4095
            const int k = idx >> 6, c = idx & 63;
            tile[k * 66 + c] = f2bf(fc2_w[(size_t)k * 1600 + c0 + c]);
        }
        __syncthreads();
        #pragma unroll
        for (int rep = 0; rep < 16; rep++) {
            const int idx = rep * 256 + t;
            const int c = idx >> 6, k = idx & 63;
            fc2_wt[(size_t)(c0 + c) * 64 + k] = tile[k * 66 + c];
        }
    } else if (b == 25) {
        #pragma unroll
        for (int rep = 0; rep < 16; rep++) {
            const int i = rep * 256 + t;           // 64k x 64n
            fc1_wt[(i & 63) * 64 + (i >> 6)] = f2bf(fc1_w[i]);
        }
    } else if (b == 26) {
        if (t < 72) stats[t] = 0.0f;
    } else {
        const int i = (b - 27) * 256 + t;
        if (i < NNODE) hist[i] = 0;
    }
}

// 8 waves/block, 16 edges/wave. fc2_wt staged in LDS (13 chunks, dbuf, XOR-swizzled).
__global__ __launch_bounds__(512, 4) void edge_fused(
    const float* __restrict__ node_attr,
    const float* __restrict__ edge_attr,
    const float* __restrict__ edge_sh,
    const int*   __restrict__ edge_index,
    const float* __restrict__ fc1_b,
    const float* __restrict__ fc2_b,
    const short* __restrict__ fc1_wt,
    const short* __restrict__ fc2_wt,
    float* __restrict__ tp_out,
    int*   __restrict__ hist)
{
    // LDS: B dbuf 2x16KB @0 | h_s 8x2KB @32768 | shb 8x256B @49152  = 51200 B
    __shared__ __align__(16) char lds[51200];
    char* cbA = lds;
    char* cbB = lds + 16384;

    const int tid  = threadIdx.x;
    const int wid  = tid >> 6;
    const int wtid = tid & 63;
    const int l15  = wtid & 15;
    const int lg   = wtid >> 4;
    const int lg4  = lg * 4;
    const int e0   = blockIdx.x * 128 + wid * 16;
    const bool active = (e0 < NEDGE);

    char*  h_s = lds + 32768 + wid * 2048;
    float* shb = (float*)(lds + 49152 + wid * 256);

    // swizzle: LDS linear dest, pre-swizzled global src; reads apply same XOR.
#define STAGE1(CH, BUF, J) do { \
        const int _o = (wid * 2 + (J)) * 1024 + wtid * 16; \
        const int _g = _o ^ (((_o >> 7) & 7) << 4); \
        stage16((const char*)fc2_wt + (CH) * 16384 + _g, (BUF) + (wid * 2 + (J)) * 1024); \
    } while (0)
#define STAGE_FULL(CH, BUF) do { STAGE1(CH, BUF, 0); STAGE1(CH, BUF, 1); } while (0)
#define STAGE_TAIL(CH, BUF) do { if (wid < 4) { STAGE1(CH, BUF, 0); STAGE1(CH, BUF, 1); } } while (0)

    STAGE_FULL(0, cbA);   // chunk 0 in flight; overlaps all of fc1/gather below

    // ---- edge meta ----
    int dst_r = 0;
    if (active && wtid < 16) {
        dst_r = edge_index[NEDGE + e0 + wtid];
        const int src = edge_index[e0 + wtid];
        const f32x4 sh_r = *(const f32x4*)(edge_sh + (size_t)(e0 + wtid) * 4);
        atomicAdd(&hist[src], 1);
        *(f32x4*)(shb + wtid * 4) = sh_r;
    }

    bf16x8 ha0, ha1;
    f32x4 shv = {0.f, 0.f, 0.f, 0.f};
    float c00r[8], cb1r[8], c10r[6], c11r[2];
    int vidx[4];
    #pragma unroll
    for (int g = 0; g < 4; g++) vidx[g] = (g * 16 + l15) * 4;

    if (active) {
        // ---- fc1 A loads ----
        const float* pa = edge_attr + (size_t)(e0 + l15) * 64 + lg * 8;
        const f32x4 va0 = *(const f32x4*)(pa);
        const f32x4 va1 = *(const f32x4*)(pa + 4);
        const f32x4 va2 = *(const f32x4*)(pa + 32);
        const f32x4 va3 = *(const f32x4*)(pa + 36);

        // ---- per-lane table slices ----
        const int dstm = __shfl(dst_r, l15, 64);
        const float* nap = node_attr + (size_t)dstm * 56;
        const f32x4 x0a = *(const f32x4*)(nap + lg * 8);
        const f32x4 x0b = *(const f32x4*)(nap + lg * 8 + 4);
        const f32x2 x1a = *(const f32x2*)(nap + 32 + lg * 6);
        const f32x2 x1b = *(const f32x2*)(nap + 34 + lg * 6);
        const f32x2 x1c = *(const f32x2*)(nap + 36 + lg * 6);
        shv = *(const f32x4*)(shb + l15 * 4);   // same-wave LDS RAW, in-order

        const float s0 = shv[0];
        #pragma unroll
        for (int j = 0; j < 4; j++) {
            cb1r[j]     = INV40f * x0a[j];
            cb1r[4 + j] = INV40f * x0b[j];
            c00r[j]     = s0 * cb1r[j];
            c00r[4 + j] = s0 * cb1r[4 + j];
        }
        const float i40s0 = INV40f * s0;
        c10r[0] = i40s0 * x1a[0]; c10r[1] = i40s0 * x1a[1]; c10r[2] = i40s0 * x1b[0];
        c10r[3] = i40s0 * x1b[1]; c10r[4] = i40s0 * x1c[0]; c10r[5] = i40s0 * x1c[1];
        c11r[0] = INV120f * (x1a[0]*shv[1] + x1a[1]*shv[2] + x1b[0]*shv[3]);
        c11r[1] = INV120f * (x1b[1]*shv[1] + x1c[0]*shv[2] + x1c[1]*shv[3]);

        // ---- fc1 -> h (relu, bf16) via per-wave swizzled LDS transpose ----
        bf16x8 a0, a1;
        #pragma unroll
        for (int i = 0; i < 4; i++) {
            a0[i] = f2bf(va0[i]); a0[4+i] = f2bf(va1[i]);
            a1[i] = f2bf(va2[i]); a1[4+i] = f2bf(va3[i]);
        }
        #pragma unroll
        for (int nf0 = 0; nf0 < 4; nf0++) {
            const bf16x8 b0 = *(const bf16x8*)(fc1_wt + (nf0*16 + l15)*64 + lg*8);
            const bf16x8 b1 = *(const bf16x8*)(fc1_wt + (nf0*16 + l15)*64 + 32 + lg*8);
            const float bias = fc1_b[nf0*16 + l15];
            f32x4 c = {bias, bias, bias, bias};
            c = MFMA16(a0, b0, c);
            c = MFMA16(a1, b1, c);
            #pragma unroll
            for (int reg = 0; reg < 4; reg++) {
                const int row = lg4 + reg;
                *(short*)(h_s + ((row*128 + (nf0*16 + l15)*2) ^ ((row & 7) << 4))) =
                    f2bf(fmaxf(c[reg], 0.0f));
            }
        }
        ha0 = *(const bf16x8*)(h_s + ((l15*128 +      lg*16) ^ ((l15 & 7) << 4)));
        ha1 = *(const bf16x8*)(h_s + ((l15*128 + 64 + lg*16) ^ ((l15 & 7) << 4)));
    }

    // ---- fc2 consume state ----
    const int s_swz = (l15 & 7) << 4;
    const int ro0 = (l15 * 128 + lg * 16) ^ s_swz;
    const int ro1 = (l15 * 128 + lg * 16 + 64) ^ s_swz;
    const int usel = lg >> 1;
    float acc0[2][4] = {{0,0,0,0},{0,0,0,0}};
    float ab1[4] = {0,0,0,0};
    float b2v[12] = {};

    auto frag = [&](const char* cb, int nfl, int nf) -> f32x4 {
        const bf16x8 b0 = *(const bf16x8*)(cb + nfl * 2048 + ro0);
        const bf16x8 b1 = *(const bf16x8*)(cb + nfl * 2048 + ro1);
        f32x4 c = *(const f32x4*)(fc2_b + nf * 16 + lg4);
        c = MFMA16(b0, ha0, c);
        return MFMA16(b1, ha1, c);
    };
    auto cons_w00 = [&](const char* cb, int ch) {
        #pragma unroll
        for (int nfl = 0; nfl < 8; nfl++) {
            const int nf = ch * 8 + nfl;
            const f32x4 c = frag(cb, nfl, nf);
            const int u = nf >> 1, hi = nf & 1;
            const float cv = bperm(vidx[u >> 3], c00r[u & 7]);
            #pragma unroll
            for (int reg = 0; reg < 4; reg++) acc0[hi][reg] += cv * c[reg];
        }
    };
    auto cons_w01 = [&](const char* cb, int rbase) {
        #pragma unroll
        for (int i = 0; i < 8; i++) {
            const int nfl_r = rbase + i;                 // region-local 0..15
            const f32x4 c = frag(cb, i, 64 + nfl_r);
            const int r0 = (2 * nfl_r) & 7, g = nfl_r >> 2;
            const float e0v = bperm(vidx[g], cb1r[r0]);
            const float e1v = bperm(vidx[g], cb1r[r0 + 1]);
            const float cv = usel ? e1v : e0v;
            #pragma unroll
            for (int reg = 0; reg < 4; reg++) ab1[reg] += cv * c[reg];
        }
    };
    auto cons_w10 = [&](const char* cb, int fb) {       // 4 frags at frag-local fb
        #pragma unroll
        for (int nfl = 0; nfl < 4; nfl++) {
            const f32x4 c = frag(cb, fb + nfl, 80 + nfl);
            #pragma unroll
            for (int i = 0; i < 3; i++) {
                const float e0v = bperm(vidx[nfl], c10r[i]);
                const float e1v = bperm(vidx[nfl], c10r[3 + i]);
                const float cv = usel ? e1v : e0v;
                #pragma unroll
                for (int reg = 0; reg < 4; reg++) b2v[reg * 3 + i] += cv * c[reg];
            }
        }
    };
    auto cons_w11 = [&](const char* cb, int fb, int ridx0, int cnt) {
        #pragma unroll
        for (int i = 0; i < 8; i++) {
            if (i >= cnt) break;
            const int ridx = ridx0 + i;                  // region-local 0..15
            const f32x4 c = frag(cb, fb + i, 84 + ridx);
            const int up = ridx >> 1, hi = ridx & 1;
            const float cv = bperm(vidx[up >> 1], c11r[up & 1]);
            #pragma unroll
            for (int reg = 0; reg < 4; reg++) acc0[hi][reg] += cv * c[reg];
        }
    };

    // ---- chunk pipeline: stage(next) ; consume(cur) ; barrier ----
    __syncthreads();                                           // chunk 0 ready
    STAGE_FULL(1,  cbB); if (active) cons_w00(cbA, 0); __syncthreads();
    STAGE_FULL(2,  cbA); if (active) cons_w00(cbB, 1); __syncthreads();
    STAGE_FULL(3,  cbB); if (active) cons_w00(cbA, 2); __syncthreads();
    STAGE_FULL(4,  cbA); if (active) cons_w00(cbB, 3); __syncthreads();
    STAGE_FULL(5,  cbB); if (active) cons_w00(cbA, 4); __syncthreads();
    STAGE_FULL(6,  cbA); if (active) cons_w00(cbB, 5); __syncthreads();
    STAGE_FULL(7,  cbB); if (active) cons_w00(cbA, 6); __syncthreads();
    STAGE_FULL(8,  cbA); if (active) cons_w00(cbB, 7); __syncthreads();
    STAGE_FULL(9,  cbB); if (active) cons_w01(cbA, 0); __syncthreads();
    STAGE_FULL(10, cbA); if (active) cons_w01(cbB, 8); __syncthreads();
    STAGE_FULL(11, cbB); if (active) { cons_w10(cbA, 0); cons_w11(cbA, 4, 0, 4); } __syncthreads();
    STAGE_TAIL(12, cbA); if (active) cons_w11(cbB, 0, 4, 8);   __syncthreads();
                         if (active) cons_w11(cbA, 0, 12, 4);

    if (!active) return;

    // ---- emit edge-ordered coalesced rows ----
    float* orow = tp_out + (size_t)(e0 + l15) * 56;
    {
        const f32x4 o0 = {acc0[0][0], acc0[0][1], acc0[0][2], acc0[0][3]};
        const f32x4 o1 = {acc0[1][0], acc0[1][1], acc0[1][2], acc0[1][3]};
        *(f32x4*)(orow + lg4)      = o0;
        *(f32x4*)(orow + 16 + lg4) = o1;
    }
    #pragma unroll
    for (int reg = 0; reg < 4; reg++) ab1[reg] += __shfl_xor(ab1[reg], 32, 64);
    #pragma unroll
    for (int m = 0; m < 12; m++) b2v[m] += __shfl_xor(b2v[m], 32, 64);
    if (lg < 2) {
        float ov[12];
        #pragma unroll
        for (int reg = 0; reg < 4; reg++) {
            ov[reg*3 + 0] = shv[1] * ab1[reg] + b2v[reg*3 + 0];
            ov[reg*3 + 1] = shv[2] * ab1[reg] + b2v[reg*3 + 1];
            ov[reg*3 + 2] = shv[3] * ab1[reg] + b2v[reg*3 + 2];
        }
        float* p1 = orow + 32 + lg * 12;
        *(f32x4*)(p1)     = f32x4{ov[0], ov[1], ov[2],  ov[3]};
        *(f32x4*)(p1 + 4) = f32x4{ov[4], ov[5], ov[6],  ov[7]};
        *(f32x4*)(p1 + 8) = f32x4{ov[8], ov[9], ov[10], ov[11]};
    }
#undef STAGE1
#undef STAGE_FULL
#undef STAGE_TAIL
}

// exclusive prefix scan of hist[10000] -> offsets[10001], cursor
__global__ __launch_bounds__(1024) void scan_hist(const int* __restrict__ hist,
                                                  int* __restrict__ offsets,
                                                  int* __restrict__ cursor) {
    __shared__ int part[1024];
    const int t = threadIdx.x;
    const int n0 = t * 10;
    int lh[10];
    int s = 0;
    if (n0 < NNODE) {
        #pragma unroll
        for (int j = 0; j < 10; j++) { lh[j] = hist[n0 + j]; s += lh[j]; }
    }
    part[t] = s;
    __syncthreads();
    for (int d = 1; d < 1024; d <<= 1) {
        const int v = (t >= d) ? part[t - d] : 0;
        __syncthreads();
        part[t] += v;
        __syncthreads();
    }
    if (n0 < NNODE) {
        int run = part[t] - s;
        #pragma unroll
        for (int j = 0; j < 10; j++) {
            offsets[n0 + j] = run; cursor[n0 + j] = run; run += lh[j];
        }
    }
    if (t == 0) offsets[NNODE] = NEDGE;
}

__global__ __launch_bounds__(256) void fill_perm(const int* __restrict__ edge_index,
                                                 int* __restrict__ cursor,
                                                 int* __restrict__ perm) {
    const int e = blockIdx.x * 256 + threadIdx.x;
    if (e < NEDGE) {
        const int s = edge_index[e];
        const int p = atomicAdd(&cursor[s], 1);
        perm[p] = e;
    }
}

// gather-based segment mean + residual + BN partial stats (16 threads/node, f32x4)
__global__ __launch_bounds__(256) void node_agg(
    const float* __restrict__ tp_out, const int* __restrict__ offsets,
    const int* __restrict__ perm,
    const float* __restrict__ node_attr, float* __restrict__ out,
    float* __restrict__ stats)
{
    __shared__ float part[72];
    const int tid = threadIdx.x;
    if (tid < 72) part[tid] = 0.0f;
    __syncthreads();
    const int n = blockIdx.x * 16 + (tid >> 4);
    const int q = tid & 15;
    if (n < NNODE && q < 14) {
        const int st = offsets[n], en = offsets[n + 1];
        f32x4 acc = {0.f, 0.f, 0.f, 0.f};
        for (int r = st; r < en; r++)
            acc += *(const f32x4*)(tp_out + (size_t)perm[r] * 56 + q * 4);
        const float inv = 1.0f / fmaxf((float)(en - st), 1.0f);
        const int c0 = q * 4;
        const f32x4 res = *(const f32x4*)(node_attr + (size_t)n * 56 + c0);
        f32x4 val;
        #pragma unroll
        for (int j = 0; j < 4; j++) {
            val[j] = acc[j] * inv + res[j];
            const int c = c0 + j;
            if (c < 32) {
                atomicAdd(&part[c], val[j]);
                atomicAdd(&part[32 + c], val[j] * val[j]);
            } else {
                atomicAdd(&part[64 + (c - 32) / 3], val[j] * val[j]);
            }
        }
        *(f32x4*)(out + (size_t)n * 56 + c0) = val;
    }
    __syncthreads();
    if (tid < 72) unsafeAtomicAdd(&stats[tid], part[tid]);
}

__global__ __launch_bounds__(256) void node_norm(
    float* __restrict__ out, const float* __restrict__ stats,
    const float* __restrict__ g0, const float* __restrict__ b0,
    const float* __restrict__ g1)
{
    const int id = blockIdx.x * 256 + threadIdx.x;
    if (id >= NNODE * 56) return;
    const int c = id % 56;
    float val = out[id];
    if (c < 32) {
        const float m   = stats[c]      * (1.0f / NNODE);
        const float ex2 = stats[32 + c] * (1.0f / NNODE);
        const float var = ex2 - m * m;
        val = (val - m) * rsqrtf(var + 1e-5f) * g0[c] + b0[c];
    } else {
        const int v = (c - 32) / 3;
        const float vn = stats[64 + v] * (1.0f / (3.0f * NNODE));
        val = val * rsqrtf(vn + 1e-5f) * g1[v];
    }
    out[id] = val;
}

extern "C" void kernel_launch(void* const* d_in, const int* in_sizes, int n_in,
                              void* d_out, int out_size, void* d_ws, size_t ws_size,
                              hipStream_t stream) {
    const float* node_attr = (const float*)d_in[0];
    const float* edge_attr = (const float*)d_in[1];
    const float* edge_sh   = (const float*)d_in[2];
    const int*   edge_index= (const int*)  d_in[3];
    const float* fc1_w     = (const float*)d_in[4];
    const float* fc1_b     = (const float*)d_in[5];
    const float* fc2_w     = (const float*)d_in[6];
    const float* fc2_b     = (const float*)d_in[7];
    const float* g0        = (const float*)d_in[8];
    const float* b0        = (const float*)d_in[9];
    const float* g1        = (const float*)d_in[10];
    float* out = (float*)d_out;

    char* ws = (char*)d_ws;
    // stats 288 | hist @288 | offsets @40288 | cursor @80320 | perm @120320 |
    // fc1_wt @520320 | fc2_wt @528512 (204800) | tp_out @733312 (22.4MB)
    float* stats   = (float*)(ws + 0);
    int*   hist    = (int*)  (ws + 288);
    int*   offsets = (int*)  (ws + 40288);
    int*   cursor  = (int*)  (ws + 80320);
    int*   perm    = (int*)  (ws + 120320);
    short* fc1_wt  = (short*)(ws + 520320);
    short* fc2_wt  = (short*)(ws + 528512);
    float* tp_out  = (float*)(ws + 733312);

    prep<<<67, 256, 0, stream>>>(fc1_w, fc2_w, fc1_wt, fc2_wt, stats, hist);
    edge_fused<<<782, 512, 0, stream>>>(node_attr, edge_attr, edge_sh, edge_index,
                                        fc1_b, fc2_b, fc1_wt, fc2_wt, tp_out, hist);
    scan_hist<<<1, 1024, 0, stream>>>(hist, offsets, cursor);
    fill_perm<<<391, 256, 0, stream>>>(edge_index, cursor, perm);
    node_agg<<<625, 256, 0, stream>>>(tp_out, offsets, perm, node_attr, out, stats);
    node_norm<<<2188, 256, 0, stream>>>(out, stats, g0, b0, g1);
}